// Round 2
// baseline (394.015 us; speedup 1.0000x reference)
//
#include <hip/hip_runtime.h>
#include <hip/hip_bf16.h>

// AdditiveRecursiveNN: binary tree of 32x32 matmuls.
// cur = relu(emb[leaf_ids])  (4096 leaves of 32x32)
// 12 levels: inp = cur[2m]+cur[2m+1]; cur = relu(inp @ W^T + b), W=emb[internal_ids[...]]
// head: logits = cur_flat @ proj_W^T + proj_b; out = (argmax, -log_softmax[label]).
// d_out is float32 x2: out[0]=prediction, out[1]=loss  (round-1 lesson: the
// 0.69921875 "error" was our bf16 pair reinterpreted as f32 -> harness reads f32).

#define EE 1024

__device__ __forceinline__ float frelu(float x) { return x > 0.f ? x : 0.f; }

// One node per block, 256 threads. out[m][i][k] = relu(b[k] + sum_j inp[i][j]*W[k][j])
template <bool LEAF>
__global__ __launch_bounds__(256) void level_kernel(
    const float* __restrict__ emb, const float* __restrict__ bias,
    const int* __restrict__ internal_ids, const int* __restrict__ leaf_ids,
    const float* __restrict__ prev, float* __restrict__ out, int ids_off) {
  __shared__ float sW[32 * 33];  // sW[j*33+k] = W[k][j] (transposed, padded)
  __shared__ float sI[32 * 33];  // sI[i*33+j] = inp[i][j]

  const int m = blockIdx.x;
  const int t = threadIdx.x;
  const int wid = internal_ids[ids_off + m];

  // Load W (row-major 32x32) transposed into LDS. float4 per thread.
  {
    const float4 wv = *(const float4*)(emb + (size_t)wid * EE + 4 * t);
    const int k = t >> 3;          // row of W
    const int j0 = (4 * t) & 31;   // col start
    sW[(j0 + 0) * 33 + k] = wv.x;
    sW[(j0 + 1) * 33 + k] = wv.y;
    sW[(j0 + 2) * 33 + k] = wv.z;
    sW[(j0 + 3) * 33 + k] = wv.w;
  }
  // Build inp = child0 + child1 (leaf level: relu(gather) each).
  {
    const int i = t >> 3;
    const int j0 = (4 * t) & 31;
    float4 a, b;
    if (LEAF) {
      const int l0 = leaf_ids[2 * m];
      const int l1 = leaf_ids[2 * m + 1];
      a = *(const float4*)(emb + (size_t)l0 * EE + 4 * t);
      b = *(const float4*)(emb + (size_t)l1 * EE + 4 * t);
      a.x = frelu(a.x); a.y = frelu(a.y); a.z = frelu(a.z); a.w = frelu(a.w);
      b.x = frelu(b.x); b.y = frelu(b.y); b.z = frelu(b.z); b.w = frelu(b.w);
    } else {
      a = *(const float4*)(prev + (size_t)(2 * m) * EE + 4 * t);
      b = *(const float4*)(prev + (size_t)(2 * m + 1) * EE + 4 * t);
    }
    sI[i * 33 + j0 + 0] = a.x + b.x;
    sI[i * 33 + j0 + 1] = a.y + b.y;
    sI[i * 33 + j0 + 2] = a.z + b.z;
    sI[i * 33 + j0 + 3] = a.w + b.w;
  }
  const float bk = bias[(size_t)wid * 32 + (t & 31)];
  __syncthreads();

  const int k = t & 31;
  const int i0 = t >> 5;  // 0..7; thread does rows i0, i0+8, i0+16, i0+24
  float a0 = bk, a1 = bk, a2 = bk, a3 = bk;
#pragma unroll
  for (int j = 0; j < 32; ++j) {
    const float w = sW[j * 33 + k];
    a0 += sI[(i0 +  0) * 33 + j] * w;
    a1 += sI[(i0 +  8) * 33 + j] * w;
    a2 += sI[(i0 + 16) * 33 + j] * w;
    a3 += sI[(i0 + 24) * 33 + j] * w;
  }
  float* o = out + (size_t)m * EE;
  o[t +   0] = frelu(a0);
  o[t + 256] = frelu(a1);
  o[t + 512] = frelu(a2);
  o[t + 768] = frelu(a3);
}

// Single block, 1024 threads: levels n=32,16,8,4,2,1 then the head.
// Stages <=16 nodes of inp per round in 64KB LDS.
__global__ __launch_bounds__(1024) void tail_kernel(
    const float* __restrict__ emb, const float* __restrict__ bias,
    const float* __restrict__ projW, const float* __restrict__ projb,
    const int* __restrict__ internal_ids, const int* __restrict__ label_ptr,
    const float* __restrict__ in64, float* __restrict__ bufA,
    float* __restrict__ bufB, float* __restrict__ out) {
  __shared__ float sInp[16 * EE];  // 64KB; also reused as head reduce scratch

  const int t = threadIdx.x;
  const float* prev = in64;  // 64 nodes from level kernel 6 (in bufB)
  int n = 32;
  int ids_off = 4032;

  for (int lev = 0; lev < 6; ++lev) {
    float* ob = (lev & 1) ? bufB : bufA;  // T32->A, T16->B, T8->A, T4->B, T2->A, T1->B
    for (int base = 0; base < n; base += 16) {
      const int nn = (n - base) < 16 ? (n - base) : 16;
      // phase 1: inp[base..base+nn) into LDS (float4)
      {
        const float4* pv = (const float4*)prev;
        float4* s4 = (float4*)sInp;
        for (int u = t; u < nn * 256; u += 1024) {
          const int mloc = u >> 8;
          const int e = u & 255;
          const int gm = base + mloc;
          float4 a = pv[(size_t)(2 * gm) * 256 + e];
          float4 b = pv[(size_t)(2 * gm) * 256 + 256 + e];
          s4[u] = make_float4(a.x + b.x, a.y + b.y, a.z + b.z, a.w + b.w);
        }
      }
      __syncthreads();
      // phase 2: nn nodes, 1024/nn threads each
      {
        const int lgn = 31 - __clz(nn);       // log2(nn)
        const int lgs = 10 - lgn;             // log2(group size)
        const int mloc = t >> lgs;
        const int g = t & ((1 << lgs) - 1);
        const int k = g & 31;
        const int rblk = g >> 5;
        const int wid = internal_ids[ids_off + base + mloc];
        const float4* Wr = (const float4*)(emb + (size_t)wid * EE + k * 32);
        float wreg[32];
#pragma unroll
        for (int q = 0; q < 8; ++q) {
          const float4 v = Wr[q];
          wreg[4 * q + 0] = v.x;
          wreg[4 * q + 1] = v.y;
          wreg[4 * q + 2] = v.z;
          wreg[4 * q + 3] = v.w;
        }
        const float bk = bias[(size_t)wid * 32 + k];
        const float* ip = sInp + mloc * EE;
        const int r = nn;  // rows per thread
        const int i0 = rblk * r;
        for (int ii = 0; ii < r; ++ii) {
          const int i = i0 + ii;
          float acc = bk;
#pragma unroll
          for (int j = 0; j < 32; ++j) acc += ip[i * 32 + j] * wreg[j];
          ob[(size_t)(base + mloc) * EE + i * 32 + k] = frelu(acc);
        }
      }
      __syncthreads();
    }
    prev = ob;
    ids_off += n;
    n >>= 1;
  }

  // Head: logits[l] = sum_t cur[t]*projW[l][t] + projb[l]; prev == bufB (1024 floats)
  {
    const float c = prev[t];
    float p0 = c * projW[t];
    float p1 = c * projW[EE + t];
#pragma unroll
    for (int off = 32; off > 0; off >>= 1) {
      p0 += __shfl_down(p0, off);
      p1 += __shfl_down(p1, off);
    }
    const int lane = t & 63;
    const int w = t >> 6;  // 16 waves
    if (lane == 0) {
      sInp[w] = p0;
      sInp[16 + w] = p1;
    }
    __syncthreads();
    if (t == 0) {
      float l0 = projb[0], l1 = projb[1];
      for (int q = 0; q < 16; ++q) {
        l0 += sInp[q];
        l1 += sInp[16 + q];
      }
      const float mx = fmaxf(l0, l1);
      const float lse = mx + logf(expf(l0 - mx) + expf(l1 - mx));
      const int lab = *label_ptr;
      const float loss = lse - (lab ? l1 : l0);
      const float pred = (l1 > l0) ? 1.f : 0.f;
      out[0] = pred;   // f32, not bf16 (harness reads d_out as float32)
      out[1] = loss;
    }
  }
}

extern "C" void kernel_launch(void* const* d_in, const int* in_sizes, int n_in,
                              void* d_out, int out_size, void* d_ws, size_t ws_size,
                              hipStream_t stream) {
  const float* emb = (const float*)d_in[0];
  const float* bias = (const float*)d_in[1];
  const float* projW = (const float*)d_in[2];
  const float* projb = (const float*)d_in[3];
  const int* leaf_ids = (const int*)d_in[4];
  const int* internal_ids = (const int*)d_in[5];
  const int* label = (const int*)d_in[6];
  float* out = (float*)d_out;

  float* bufA = (float*)d_ws;                 // 8 MB region
  float* bufB = bufA + (size_t)2048 * EE;     // 4 MB region

  // Level 1 (n=2048): leaves fused. ids [0,2048) -> bufA
  level_kernel<true><<<2048, 256, 0, stream>>>(emb, bias, internal_ids, leaf_ids,
                                               nullptr, bufA, 0);
  // n=1024: ids [2048,3072), bufA -> bufB
  level_kernel<false><<<1024, 256, 0, stream>>>(emb, bias, internal_ids, nullptr,
                                                bufA, bufB, 2048);
  // n=512: bufB -> bufA
  level_kernel<false><<<512, 256, 0, stream>>>(emb, bias, internal_ids, nullptr,
                                               bufB, bufA, 3072);
  // n=256: bufA -> bufB
  level_kernel<false><<<256, 256, 0, stream>>>(emb, bias, internal_ids, nullptr,
                                               bufA, bufB, 3584);
  // n=128: bufB -> bufA
  level_kernel<false><<<128, 256, 0, stream>>>(emb, bias, internal_ids, nullptr,
                                               bufB, bufA, 3840);
  // n=64: bufA -> bufB
  level_kernel<false><<<64, 256, 0, stream>>>(emb, bias, internal_ids, nullptr,
                                              bufA, bufB, 3968);
  // Tail: n=32..1 + head. Reads bufB (64 nodes), ping-pongs A/B, writes out.
  tail_kernel<<<1, 1024, 0, stream>>>(emb, bias, projW, projb, internal_ids, label,
                                      bufB, bufA, bufB, out);
}

// Round 4
// 302.565 us; speedup vs baseline: 1.3022x; 1.3022x over previous
//
#include <hip/hip_runtime.h>

// AdditiveRecursiveNN: binary tree of 32x32 matmuls, subtree-blocked.
//   cur = relu(emb[leaf_ids]) (4096 leaves); 12 levels of
//   inp = cur[2m]+cur[2m+1]; cur = relu(einsum('ij,kj->ik', inp, W) + b)
//   head: logits = flat(cur) @ projW^T + projb -> (argmax, -log_softmax[label]) as f32x2.
//
// 3 kernels, each computing 4 tree levels inside LDS (8->4->2->1 nodes/block):
//   K1 <0>: 256 blocks, leaves + n=2048,1024,512,256 -> 256 nodes (1 MB)
//   K2 <1>: 16 blocks,  n=128,64,32,16               -> 16 nodes (64 KB)
//   K3 <2>: 1 block,    n=8,4,2,1 + head             -> out[2]
// Only ~1 MB of intermediates touch global; gathers (~33 MB) are irreducible.
// (Round 3 was a GPUAcquisitionTimeout — this source is the unchanged round-3
// kernel, resubmitted to get its first hardware measurement.)

#define NS 1056  // per-node LDS stride: 32 rows x (32+1) padded cols

__device__ __forceinline__ float frelu(float x) { return x > 0.f ? x : 0.f; }

// MODE: 0 = leaf staging (gather emb[leaf_ids] + relu), 1 = mid, 2 = mid + head
template <int MODE>
__global__ __launch_bounds__(512) void subtree_kernel(
    const float* __restrict__ emb, const float* __restrict__ bias,
    const int* __restrict__ internal_ids, const int* __restrict__ leaf_ids,
    const float* __restrict__ prev, float* __restrict__ outg, int4 id_off,
    const float* __restrict__ projW, const float* __restrict__ projb,
    const int* __restrict__ label_ptr, float* __restrict__ outres) {
  __shared__ float A[8 * NS];  // level inputs  (padded [32][33] per node)
  __shared__ float B[8 * NS];  // level outputs
  __shared__ float red[16];

  const int b = blockIdx.x;
  const int t = threadIdx.x;

  // ---- stage: A[g] = child0 + child1 for 8 nodes (leaf level applies relu) ----
  {
    const int g = t >> 6, u = t & 63;
    const float4* s0;
    const float4* s1;
    if (MODE == 0) {
      const int l0 = leaf_ids[16 * b + 2 * g];
      const int l1 = leaf_ids[16 * b + 2 * g + 1];
      s0 = (const float4*)(emb + (size_t)l0 * 1024);
      s1 = (const float4*)(emb + (size_t)l1 * 1024);
    } else {
      s0 = (const float4*)(prev + (size_t)(16 * b + 2 * g) * 1024);
      s1 = (const float4*)(prev + (size_t)(16 * b + 2 * g + 1) * 1024);
    }
#pragma unroll
    for (int q = 0; q < 4; ++q) {
      const int e4 = u + 64 * q;
      const int e = 4 * e4;
      const int i = e >> 5, j = e & 31;
      float4 a = s0[e4];
      float4 c = s1[e4];
      if (MODE == 0) {
        a.x = frelu(a.x); a.y = frelu(a.y); a.z = frelu(a.z); a.w = frelu(a.w);
        c.x = frelu(c.x); c.y = frelu(c.y); c.z = frelu(c.z); c.w = frelu(c.w);
      }
      float* d = A + g * NS + i * 33 + j;
      d[0] = a.x + c.x; d[1] = a.y + c.y; d[2] = a.z + c.z; d[3] = a.w + c.w;
    }
  }
  __syncthreads();

  // ---- 4 levels in LDS: nl = 8,4,2,1 nodes ----
  const int offs[4] = {id_off.x, id_off.y, id_off.z, id_off.w};
#pragma unroll
  for (int L = 0; L < 4; ++L) {
    const int nl = 8 >> L;
    const int tpn = 512 / nl;        // threads per node
    const int node = t / tpn;
    const int g = t % tpn;
    const int k = g & 31;            // output column (W row)
    const int rb = g >> 5;           // row block
    const int rpt = 1024 / tpn;      // rows per thread
    const int wid = internal_ids[offs[L] + nl * b + node];

    float w[32];
    const float4* Wr = (const float4*)(emb + (size_t)wid * 1024 + k * 32);
#pragma unroll
    for (int q = 0; q < 8; ++q) {
      const float4 v = Wr[q];
      w[4 * q] = v.x; w[4 * q + 1] = v.y; w[4 * q + 2] = v.z; w[4 * q + 3] = v.w;
    }
    const float bk = bias[(size_t)wid * 32 + k];

    const float* ip = A + node * NS;
    float* op = B + node * NS;
    const int i0 = rb * rpt;
#pragma unroll
    for (int ii = 0; ii < rpt; ++ii) {
      const int i = i0 + ii;
      float acc = bk;
#pragma unroll
      for (int j = 0; j < 32; ++j) acc += ip[i * 33 + j] * w[j];
      op[i * 33 + k] = frelu(acc);
    }
    __syncthreads();

    if (L < 3) {  // next level inputs: A[m] = B[2m] + B[2m+1]
      const int nl2 = nl >> 1;
      for (int u = t; u < nl2 * 1024; u += 512) {
        const int m = u >> 10, e = u & 1023;
        const int idx = (e >> 5) * 33 + (e & 31);
        A[m * NS + idx] = B[2 * m * NS + idx] + B[(2 * m + 1) * NS + idx];
      }
      __syncthreads();
    }
  }

  if (MODE == 2) {
    // head on B[0] (padded): logits[l] = projb[l] + sum_e cur_flat[e]*projW[l][e]
    float p0 = 0.f, p1 = 0.f;
#pragma unroll
    for (int r = 0; r < 2; ++r) {
      const int e = t + 512 * r;
      const float c = B[(e >> 5) * 33 + (e & 31)];
      p0 += c * projW[e];
      p1 += c * projW[1024 + e];
    }
#pragma unroll
    for (int off = 32; off; off >>= 1) {
      p0 += __shfl_down(p0, off);
      p1 += __shfl_down(p1, off);
    }
    if ((t & 63) == 0) { red[t >> 6] = p0; red[8 + (t >> 6)] = p1; }
    __syncthreads();
    if (t == 0) {
      float l0 = projb[0], l1 = projb[1];
#pragma unroll
      for (int q = 0; q < 8; ++q) { l0 += red[q]; l1 += red[8 + q]; }
      const float mx = fmaxf(l0, l1);
      const float lse = mx + logf(expf(l0 - mx) + expf(l1 - mx));
      const int lab = *label_ptr;
      outres[0] = (l1 > l0) ? 1.f : 0.f;  // argmax (ties -> 0, matches np)
      outres[1] = lse - (lab ? l1 : l0);  // -log_softmax[label]
    }
  } else {
    // write block's final node (B[0]) compact to outg[b]
    float4* o4 = (float4*)(outg + (size_t)b * 1024);
    for (int e4 = t; e4 < 256; e4 += 512) {
      const int e = 4 * e4;
      const float* s = B + (e >> 5) * 33 + (e & 31);
      o4[e4] = make_float4(s[0], s[1], s[2], s[3]);
    }
  }
}

extern "C" void kernel_launch(void* const* d_in, const int* in_sizes, int n_in,
                              void* d_out, int out_size, void* d_ws, size_t ws_size,
                              hipStream_t stream) {
  const float* emb = (const float*)d_in[0];
  const float* bias = (const float*)d_in[1];
  const float* projW = (const float*)d_in[2];
  const float* projb = (const float*)d_in[3];
  const int* leaf_ids = (const int*)d_in[4];
  const int* internal_ids = (const int*)d_in[5];
  const int* label = (const int*)d_in[6];
  float* out = (float*)d_out;

  float* prev256 = (float*)d_ws;                  // 256 nodes x 4 KB = 1 MB
  float* prev16 = prev256 + (size_t)256 * 1024;   // 16 nodes x 4 KB

  // id offsets per level: 2048@0, 1024@2048, 512@3072, 256@3584,
  // 128@3840, 64@3968, 32@4032, 16@4064, 8@4080, 4@4088, 2@4092, 1@4094
  subtree_kernel<0><<<256, 512, 0, stream>>>(
      emb, bias, internal_ids, leaf_ids, nullptr, prev256,
      make_int4(0, 2048, 3072, 3584), nullptr, nullptr, nullptr, nullptr);
  subtree_kernel<1><<<16, 512, 0, stream>>>(
      emb, bias, internal_ids, nullptr, prev256, prev16,
      make_int4(3840, 3968, 4032, 4064), nullptr, nullptr, nullptr, nullptr);
  subtree_kernel<2><<<1, 512, 0, stream>>>(
      emb, bias, internal_ids, nullptr, prev16, nullptr,
      make_int4(4080, 4088, 4092, 4094), projW, projb, label, out);
}